// Round 2
// baseline (571.177 us; speedup 1.0000x reference)
//
#include <hip/hip_runtime.h>
#include <math.h>

#define NPATH 23
#define NEDGE 50000
#define NCHAN 32
#define NWROW 736      // 23*32 weight row length
#define OUTW  99       // concatenated output width
#define CGTOT 1875     // total CG elements across paths
#define TTOT  439      // total T = sum n1*n3
#define EPB   4        // edges per block (main kernel)

// Path tables (derived from the reference's _build_paths; verified in round 0)
constexpr int L1[NPATH]    = {0,0,0,0,1,1,1,1,1,1,2,2,2,2,2,2,2,3,3,3,3,3,3};
constexpr int L2[NPATH]    = {0,1,2,3,0,1,1,2,2,3,0,1,1,2,2,3,3,0,1,2,2,3,3};
constexpr int L3[NPATH]    = {0,1,2,3,1,0,2,1,3,2,2,1,3,0,2,1,3,3,2,1,3,0,2};
constexpr int POS[NPATH]   = {0,4,10,17,5,1,11,6,18,12,13,7,19,2,14,8,20,21,15,9,22,3,16};
constexpr int OOFF[NPATH]  = {0,4,7,12,19,1,34,22,39,46,51,31,61,2,73,25,78,85,68,28,92,3,56};
constexpr int CGOFF[NPATH] = {0,1,10,35,84,93,102,147,192,297,402,427,472,577,602,727,832,1077,1126,1231,1336,1581,1630};
constexpr int TOFF[NPATH]  = {0,1,4,9,16,25,28,43,52,73,88,113,128,163,168,193,208,243,292,327,348,397,404};
constexpr int LOFF[4]      = {0,1,4,9};  // offset of l-block within the 16-dim irrep axis

// FMA-balanced path split between the two sub-thread halves (220 vs 219 FMAs)
#define SUBMASK0 0x0007871Fu
#define SUBMASK1 0x007878E0u

__device__ __forceinline__ int imx(int a, int b){ return a > b ? a : b; }
__device__ __forceinline__ int imn(int a, int b){ return a < b ? a : b; }

__device__ __forceinline__ double factd(int n){
    double r = 1.0;
    for(int i = 2; i <= n; ++i) r *= (double)i;
    return r;
}

// ---------------------------------------------------------------------------
// Setup kernel: replicate the reference's _wigner_3j EXACTLY (verified R0).
// ---------------------------------------------------------------------------
__global__ __launch_bounds__(512) void cg_setup(float* __restrict__ cg_out){
    const int p  = blockIdx.x;
    const int j1 = L1[p], j2 = L2[p], j3 = L3[p];
    const int n1 = 2*j1+1, n2 = 2*j2+1, n3 = 2*j3+1;
    const int ntot = n1*n2*n3;
    const int t = threadIdx.x;

    __shared__ double scg[343];
    __shared__ double qre[3][49];
    __shared__ double qim[3][49];
    __shared__ double red[512];

    if(t < ntot){
        int a   = t / (n2*n3);
        int rem = t - a*(n2*n3);
        int b   = rem / n3;
        int g   = rem - b*n3;
        int m1 = a - j1, m2 = b - j2, m3 = g - j3;
        double val = 0.0;
        if(m1 + m2 == m3){
            int vmin = imx(imx(-j1 + j2 + m3, -j1 + m1), 0);
            int vmax = imn(imn(j2 + j3 + m1, j3 - j1 + j2), j3 + m3);
            double C = sqrt((2.0*j3 + 1.0) * factd(j3 + j1 - j2) * factd(j3 - j1 + j2)
                            * factd(j1 + j2 - j3) / factd(j1 + j2 + j3 + 1));
            C *= sqrt(factd(j3 + m3) * factd(j3 - m3) * factd(j1 - m1)
                      * factd(j1 + m1) * factd(j2 - m2) * factd(j2 + m2));
            double S = 0.0;
            for(int v = vmin; v <= vmax; ++v){
                double sgn = ((v + j2 + m2) & 1) ? -1.0 : 1.0;
                S += sgn * factd(j2 + j3 + m1 - v) * factd(j1 - m1 + v)
                     / (factd(v) * factd(j3 - j1 + j2 - v) * factd(j3 + m3 - v)
                        * factd(v + j1 - j2 - m3));
            }
            val = C * S;
        }
        scg[t] = val;
    }

    if(t < 3){
        int l = (t == 0) ? j1 : ((t == 1) ? j2 : j3);
        int n = 2*l + 1;
        double* QR = qre[t];
        double* QI = qim[t];
        for(int i = 0; i < 49; ++i){ QR[i] = 0.0; QI[i] = 0.0; }
        const double is2 = 0.70710678118654752440;
        for(int m = -l; m < 0; ++m){
            QR[(l+m)*n + (l-m)] = is2;
            QI[(l+m)*n + (l+m)] = -is2;
        }
        QR[l*n + l] = 1.0;
        for(int m = 1; m <= l; ++m){
            double s = (m & 1) ? -1.0 : 1.0;
            QR[(l+m)*n + (l+m)] = s * is2;
            QI[(l+m)*n + (l-m)] = s * is2;
        }
        double fr, fi;
        switch(l & 3){
            case 0: fr = 1.0;  fi = 0.0;  break;
            case 1: fr = 0.0;  fi = -1.0; break;
            case 2: fr = -1.0; fi = 0.0;  break;
            default: fr = 0.0; fi = 1.0;  break;
        }
        for(int i = 0; i < n*n; ++i){
            double re = QR[i], im = QI[i];
            QR[i] = re*fr - im*fi;
            QI[i] = re*fi + im*fr;
        }
    }
    __syncthreads();

    double val = 0.0;
    if(t < ntot){
        int j   = t / (n2*n3);
        int rem = t - j*(n2*n3);
        int lq  = rem / n3;
        int m   = rem - lq*n3;
        double acc = 0.0;
        for(int i = 0; i < n1; ++i){
            double q1r = qre[0][i*n1 + j], q1i = qim[0][i*n1 + j];
            if(q1r == 0.0 && q1i == 0.0) continue;
            for(int k = 0; k < n2; ++k){
                double q2r = qre[1][k*n2 + lq], q2i = qim[1][k*n2 + lq];
                if(q2r == 0.0 && q2i == 0.0) continue;
                double ar = q1r*q2r - q1i*q2i;
                double ai = q1r*q2i + q1i*q2r;
                for(int n = 0; n < n3; ++n){
                    double cv = scg[(i*n2 + k)*n3 + n];
                    if(cv == 0.0) continue;
                    double q3r = qre[2][n*n3 + m];
                    double q3i = -qim[2][n*n3 + m];
                    acc += cv * (ar*q3r - ai*q3i);
                }
            }
        }
        val = acc;
    }

    red[t] = val * val;
    __syncthreads();
    for(int s = 256; s > 0; s >>= 1){
        if(t < s) red[t] += red[t + s];
        __syncthreads();
    }
    double nrm = sqrt(red[0]);
    if(t < ntot){
        cg_out[CGOFF[p] + t] = (float)(val * sqrt(2.0*j3 + 1.0) / nrm);
    }
}

// ---------------------------------------------------------------------------
// Main kernel: 4 edges/block, 256 threads. Two sub-threads per (edge,channel)
// split the 23 paths (FMA-balanced). Outputs staged in LDS (bank-conflict-free
// writes: c*99 -> 3c mod 32 covers all banks), flushed with coalesced float4.
// ---------------------------------------------------------------------------
__global__ __launch_bounds__(256) void tp_main(
    const float* __restrict__ x, const float* __restrict__ y,
    const float* __restrict__ w, const float* __restrict__ cg,
    float* __restrict__ out)
{
    __shared__ __align__(16) float obuf[EPB*NCHAN*OUTW];  // 12672 floats, 50.7 KB
    __shared__ float Ts[EPB*TTOT];                        // 1756 floats, 7.0 KB
    __shared__ float ys[EPB*16];                          // 64 floats

    const int tid = threadIdx.x;
    const int e0  = blockIdx.x * EPB;

    const int sub = tid >> 7;         // path-half
    const int r   = tid & 127;
    const int el  = r >> 5;           // edge within block
    const int c   = r & 31;           // channel
    const int e   = e0 + el;

    // x fragment: 16 consecutive floats, 64B aligned (issued early, used late)
    const float4* xp = reinterpret_cast<const float4*>(x + (size_t)(e*NCHAN + c)*16);
    float4 x0 = xp[0], x1 = xp[1], x2 = xp[2], x3 = xp[3];

    if(tid < EPB*16) ys[tid] = y[e0*16 + tid];
    __syncthreads();

    // Phase B: T[el][p][i][k] = sum_j y[el][o2+j] * CG[p][i][j][k]
    for(int u = tid; u < EPB*TTOT; u += 256){
        int eli = u / TTOT;
        int v   = u - eli*TTOT;
        int p   = 0;
        while(p < NPATH-1 && TOFF[p+1] <= v) ++p;
        int rel = v - TOFF[p];
        int n2  = 2*L2[p] + 1;
        int n3  = 2*L3[p] + 1;
        int i   = rel / n3;
        int k   = rel - i*n3;
        int o2  = LOFF[L2[p]];
        const float* cgp = &cg[CGOFF[p]];
        float acc = 0.f;
        for(int j = 0; j < n2; ++j)
            acc += ys[eli*16 + o2 + j] * cgp[(i*n2 + j)*n3 + k];
        Ts[u] = acc;
    }
    __syncthreads();

    // Phase C: compute this thread's path subset, stage into LDS
    float xr[16];
    xr[0]=x0.x;  xr[1]=x0.y;  xr[2]=x0.z;  xr[3]=x0.w;
    xr[4]=x1.x;  xr[5]=x1.y;  xr[6]=x1.z;  xr[7]=x1.w;
    xr[8]=x2.x;  xr[9]=x2.y;  xr[10]=x2.z; xr[11]=x2.w;
    xr[12]=x3.x; xr[13]=x3.y; xr[14]=x3.z; xr[15]=x3.w;

    const unsigned mask = sub ? SUBMASK1 : SUBMASK0;
    const float* wrow = w + (size_t)e*NWROW + c;
    const float* Te = Ts + el*TTOT;
    float* ob = obuf + el*(NCHAN*OUTW) + c*OUTW;

    #pragma unroll
    for(int p = 0; p < NPATH; ++p){
        if(!((mask >> p) & 1u)) continue;
        const int n1 = 2*L1[p] + 1;
        const int n3 = 2*L3[p] + 1;
        const int o1 = LOFF[L1[p]];
        const float wp = wrow[POS[p]*NCHAN];
        const float* Tp = Te + TOFF[p];
        #pragma unroll
        for(int k = 0; k < n3; ++k){
            float acc = 0.f;
            #pragma unroll
            for(int i = 0; i < n1; ++i)
                acc = fmaf(xr[o1 + i], Tp[i*n3 + k], acc);
            ob[OOFF[p] + k] = wp * acc;
        }
    }
    __syncthreads();

    // Flush: 12672 contiguous floats -> coalesced float4 stores (64B-aligned)
    const float4* ob4 = reinterpret_cast<const float4*>(obuf);
    float4* o4 = reinterpret_cast<float4*>(out + (size_t)blockIdx.x * (EPB*NCHAN*OUTW));
    #pragma unroll 4
    for(int idx = tid; idx < EPB*NCHAN*OUTW/4; idx += 256)
        o4[idx] = ob4[idx];
}

extern "C" void kernel_launch(void* const* d_in, const int* in_sizes, int n_in,
                              void* d_out, int out_size, void* d_ws, size_t ws_size,
                              hipStream_t stream)
{
    const float* x  = (const float*)d_in[0];
    const float* y  = (const float*)d_in[1];
    const float* wt = (const float*)d_in[2];
    float* out = (float*)d_out;
    float* cgw = (float*)d_ws;   // 1875 floats = 7.5 KB of scratch

    cg_setup<<<NPATH, 512, 0, stream>>>(cgw);
    tp_main<<<NEDGE/EPB, 256, 0, stream>>>(x, y, wt, cgw, out);
}

// Round 3
// 414.195 us; speedup vs baseline: 1.3790x; 1.3790x over previous
//
#include <hip/hip_runtime.h>
#include <math.h>

#define NPATH 23
#define NEDGE 50000
#define NCHAN 32
#define NWROW 736      // 23*32 weight row length
#define OUTW  99       // concatenated output width
#define CGTOT 1875     // total CG elements across paths
#define TTOT  439      // total T = sum n1*n3
#define EPB   2        // edges per block (main kernel)

// Path tables (derived from the reference's _build_paths; verified in round 0)
constexpr int L1[NPATH]    = {0,0,0,0,1,1,1,1,1,1,2,2,2,2,2,2,2,3,3,3,3,3,3};
constexpr int L2[NPATH]    = {0,1,2,3,0,1,1,2,2,3,0,1,1,2,2,3,3,0,1,2,2,3,3};
constexpr int L3[NPATH]    = {0,1,2,3,1,0,2,1,3,2,2,1,3,0,2,1,3,3,2,1,3,0,2};
constexpr int POS[NPATH]   = {0,4,10,17,5,1,11,6,18,12,13,7,19,2,14,8,20,21,15,9,22,3,16};
constexpr int OOFF[NPATH]  = {0,4,7,12,19,1,34,22,39,46,51,31,61,2,73,25,78,85,68,28,92,3,56};
constexpr int CGOFF[NPATH] = {0,1,10,35,84,93,102,147,192,297,402,427,472,577,602,727,832,1077,1126,1231,1336,1581,1630};
constexpr int TOFF[NPATH]  = {0,1,4,9,16,25,28,43,52,73,88,113,128,163,168,193,208,243,292,327,348,397,404};
constexpr int LOFF[4]      = {0,1,4,9};  // offset of l-block within the 16-dim irrep axis

// 4-way path split, one group per WAVE (wave-uniform mask, no divergence).
// FMA balance: 114 / 112 / 105 / 108
constexpr unsigned GMASK[4] = {0xE0010u, 0x700100u, 0x7C00u, 0x182EFu};

__device__ __forceinline__ int imx(int a, int b){ return a > b ? a : b; }
__device__ __forceinline__ int imn(int a, int b){ return a < b ? a : b; }

__device__ __forceinline__ double factd(int n){
    double r = 1.0;
    for(int i = 2; i <= n; ++i) r *= (double)i;
    return r;
}

// ---------------------------------------------------------------------------
// Setup kernel: replicate the reference's _wigner_3j EXACTLY (verified R0).
// ---------------------------------------------------------------------------
__global__ __launch_bounds__(512) void cg_setup(float* __restrict__ cg_out){
    const int p  = blockIdx.x;
    const int j1 = L1[p], j2 = L2[p], j3 = L3[p];
    const int n1 = 2*j1+1, n2 = 2*j2+1, n3 = 2*j3+1;
    const int ntot = n1*n2*n3;
    const int t = threadIdx.x;

    __shared__ double scg[343];
    __shared__ double qre[3][49];
    __shared__ double qim[3][49];
    __shared__ double red[512];

    if(t < ntot){
        int a   = t / (n2*n3);
        int rem = t - a*(n2*n3);
        int b   = rem / n3;
        int g   = rem - b*n3;
        int m1 = a - j1, m2 = b - j2, m3 = g - j3;
        double val = 0.0;
        if(m1 + m2 == m3){
            int vmin = imx(imx(-j1 + j2 + m3, -j1 + m1), 0);
            int vmax = imn(imn(j2 + j3 + m1, j3 - j1 + j2), j3 + m3);
            double C = sqrt((2.0*j3 + 1.0) * factd(j3 + j1 - j2) * factd(j3 - j1 + j2)
                            * factd(j1 + j2 - j3) / factd(j1 + j2 + j3 + 1));
            C *= sqrt(factd(j3 + m3) * factd(j3 - m3) * factd(j1 - m1)
                      * factd(j1 + m1) * factd(j2 - m2) * factd(j2 + m2));
            double S = 0.0;
            for(int v = vmin; v <= vmax; ++v){
                double sgn = ((v + j2 + m2) & 1) ? -1.0 : 1.0;
                S += sgn * factd(j2 + j3 + m1 - v) * factd(j1 - m1 + v)
                     / (factd(v) * factd(j3 - j1 + j2 - v) * factd(j3 + m3 - v)
                        * factd(v + j1 - j2 - m3));
            }
            val = C * S;
        }
        scg[t] = val;
    }

    if(t < 3){
        int l = (t == 0) ? j1 : ((t == 1) ? j2 : j3);
        int n = 2*l + 1;
        double* QR = qre[t];
        double* QI = qim[t];
        for(int i = 0; i < 49; ++i){ QR[i] = 0.0; QI[i] = 0.0; }
        const double is2 = 0.70710678118654752440;
        for(int m = -l; m < 0; ++m){
            QR[(l+m)*n + (l-m)] = is2;
            QI[(l+m)*n + (l+m)] = -is2;
        }
        QR[l*n + l] = 1.0;
        for(int m = 1; m <= l; ++m){
            double s = (m & 1) ? -1.0 : 1.0;
            QR[(l+m)*n + (l+m)] = s * is2;
            QI[(l+m)*n + (l-m)] = s * is2;
        }
        double fr, fi;
        switch(l & 3){
            case 0: fr = 1.0;  fi = 0.0;  break;
            case 1: fr = 0.0;  fi = -1.0; break;
            case 2: fr = -1.0; fi = 0.0;  break;
            default: fr = 0.0; fi = 1.0;  break;
        }
        for(int i = 0; i < n*n; ++i){
            double re = QR[i], im = QI[i];
            QR[i] = re*fr - im*fi;
            QI[i] = re*fi + im*fr;
        }
    }
    __syncthreads();

    double val = 0.0;
    if(t < ntot){
        int j   = t / (n2*n3);
        int rem = t - j*(n2*n3);
        int lq  = rem / n3;
        int m   = rem - lq*n3;
        double acc = 0.0;
        for(int i = 0; i < n1; ++i){
            double q1r = qre[0][i*n1 + j], q1i = qim[0][i*n1 + j];
            if(q1r == 0.0 && q1i == 0.0) continue;
            for(int k = 0; k < n2; ++k){
                double q2r = qre[1][k*n2 + lq], q2i = qim[1][k*n2 + lq];
                if(q2r == 0.0 && q2i == 0.0) continue;
                double ar = q1r*q2r - q1i*q2i;
                double ai = q1r*q2i + q1i*q2r;
                for(int n = 0; n < n3; ++n){
                    double cv = scg[(i*n2 + k)*n3 + n];
                    if(cv == 0.0) continue;
                    double q3r = qre[2][n*n3 + m];
                    double q3i = -qim[2][n*n3 + m];
                    acc += cv * (ar*q3r - ai*q3i);
                }
            }
        }
        val = acc;
    }

    red[t] = val * val;
    __syncthreads();
    for(int s = 256; s > 0; s >>= 1){
        if(t < s) red[t] += red[t + s];
        __syncthreads();
    }
    double nrm = sqrt(red[0]);
    if(t < ntot){
        cg_out[CGOFF[p] + t] = (float)(val * sqrt(2.0*j3 + 1.0) / nrm);
    }
}

// ---------------------------------------------------------------------------
// Main kernel: 2 edges/block, 256 threads. Wave w owns path-group w
// (wave-uniform mask -> no divergence). Lane = (el, c). Outputs staged in a
// 25.3 KB LDS tile (conflict-free: banks 3c+col mod 32, 2-way over el = free),
// flushed with coalesced float4 stores. Total LDS ~28.3 KB -> 5 blocks/CU.
// ---------------------------------------------------------------------------
__global__ __launch_bounds__(256, 5) void tp_main(
    const float* __restrict__ x, const float* __restrict__ y,
    const float* __restrict__ w, const float* __restrict__ cg,
    float* __restrict__ out)
{
    __shared__ __align__(16) float obuf[EPB*NCHAN*OUTW];  // 6336 floats, 25.3 KB
    __shared__ float Ts[EPB*TTOT];                        // 878 floats, 3.5 KB
    __shared__ float ys[EPB*16];                          // 32 floats

    const int tid = threadIdx.x;
    const int e0  = blockIdx.x * EPB;

    const int c   = tid & 31;          // channel
    const int el  = (tid >> 5) & 1;    // edge within block
    const int grp = tid >> 6;          // wave id = path group
    const int e   = e0 + el;

    // issue x loads early; consumed after the Ts barrier
    const float4* xp = reinterpret_cast<const float4*>(x + (size_t)(e*NCHAN + c)*16);
    float4 x0 = xp[0], x1 = xp[1], x2 = xp[2], x3 = xp[3];

    if(tid < EPB*16) ys[tid] = y[e0*16 + tid];
    __syncthreads();

    // Phase B: T[el][p][i][k] = sum_j y[el][o2+j] * CG[p][i][j][k]  (878 items)
    for(int u = tid; u < EPB*TTOT; u += 256){
        int eli = u / TTOT;
        int v   = u - eli*TTOT;
        int p   = 0;
        while(p < NPATH-1 && TOFF[p+1] <= v) ++p;
        int rel = v - TOFF[p];
        int n2  = 2*L2[p] + 1;
        int n3  = 2*L3[p] + 1;
        int i   = rel / n3;
        int k   = rel - i*n3;
        int o2  = LOFF[L2[p]];
        const float* cgp = &cg[CGOFF[p]];
        float acc = 0.f;
        for(int j = 0; j < n2; ++j)
            acc += ys[eli*16 + o2 + j] * cgp[(i*n2 + j)*n3 + k];
        Ts[u] = acc;
    }
    __syncthreads();

    // Phase C: this wave's path group, staged into LDS
    float xr[16];
    xr[0]=x0.x;  xr[1]=x0.y;  xr[2]=x0.z;  xr[3]=x0.w;
    xr[4]=x1.x;  xr[5]=x1.y;  xr[6]=x1.z;  xr[7]=x1.w;
    xr[8]=x2.x;  xr[9]=x2.y;  xr[10]=x2.z; xr[11]=x2.w;
    xr[12]=x3.x; xr[13]=x3.y; xr[14]=x3.z; xr[15]=x3.w;

    const unsigned mask = GMASK[grp];
    const float* wrow = w + (size_t)e*NWROW + c;
    const float* Te = Ts + el*TTOT;
    float* ob = obuf + el*(NCHAN*OUTW) + c*OUTW;

    #pragma unroll
    for(int p = 0; p < NPATH; ++p){
        if(!((mask >> p) & 1u)) continue;
        const int n1 = 2*L1[p] + 1;
        const int n3 = 2*L3[p] + 1;
        const int o1 = LOFF[L1[p]];
        const float wp = wrow[POS[p]*NCHAN];
        const float* Tp = Te + TOFF[p];
        #pragma unroll
        for(int k = 0; k < n3; ++k){
            float acc = 0.f;
            #pragma unroll
            for(int i = 0; i < n1; ++i)
                acc = fmaf(xr[o1 + i], Tp[i*n3 + k], acc);
            ob[OOFF[p] + k] = wp * acc;
        }
    }
    __syncthreads();

    // Flush: 6336 contiguous floats -> coalesced float4 stores (64B-aligned)
    const float4* ob4 = reinterpret_cast<const float4*>(obuf);
    float4* o4 = reinterpret_cast<float4*>(out + (size_t)blockIdx.x * (EPB*NCHAN*OUTW));
    #pragma unroll
    for(int idx = tid; idx < EPB*NCHAN*OUTW/4; idx += 256)
        o4[idx] = ob4[idx];
}

extern "C" void kernel_launch(void* const* d_in, const int* in_sizes, int n_in,
                              void* d_out, int out_size, void* d_ws, size_t ws_size,
                              hipStream_t stream)
{
    const float* x  = (const float*)d_in[0];
    const float* y  = (const float*)d_in[1];
    const float* wt = (const float*)d_in[2];
    float* out = (float*)d_out;
    float* cgw = (float*)d_ws;   // 1875 floats = 7.5 KB of scratch

    cg_setup<<<NPATH, 512, 0, stream>>>(cgw);
    tp_main<<<NEDGE/EPB, 256, 0, stream>>>(x, y, wt, cgw, out);
}

// Round 4
// 285.130 us; speedup vs baseline: 2.0032x; 1.4527x over previous
//
#include <hip/hip_runtime.h>
#include <math.h>

#define NPATH 23
#define NEDGE 50000
#define NCHAN 32
#define NWROW 736      // 23*32 weight row length
#define OUTW  99       // concatenated output width
#define CGTOT 1875     // total CG elements across paths
#define TTOT  439      // total T = sum n1*n3
#define EPB   2        // edges per block (main kernel)

// Path tables (derived from the reference's _build_paths; verified in round 0)
constexpr int L1[NPATH]    = {0,0,0,0,1,1,1,1,1,1,2,2,2,2,2,2,2,3,3,3,3,3,3};
constexpr int L2[NPATH]    = {0,1,2,3,0,1,1,2,2,3,0,1,1,2,2,3,3,0,1,2,2,3,3};
constexpr int L3[NPATH]    = {0,1,2,3,1,0,2,1,3,2,2,1,3,0,2,1,3,3,2,1,3,0,2};
constexpr int POS[NPATH]   = {0,4,10,17,5,1,11,6,18,12,13,7,19,2,14,8,20,21,15,9,22,3,16};
constexpr int OOFF[NPATH]  = {0,4,7,12,19,1,34,22,39,46,51,31,61,2,73,25,78,85,68,28,92,3,56};
constexpr int CGOFF[NPATH] = {0,1,10,35,84,93,102,147,192,297,402,427,472,577,602,727,832,1077,1126,1231,1336,1581,1630};
constexpr int TOFF[NPATH]  = {0,1,4,9,16,25,28,43,52,73,88,113,128,163,168,193,208,243,292,327,348,397,404};
constexpr int LOFF[4]      = {0,1,4,9};  // offset of l-block within the 16-dim irrep axis

// 4-way path split, one group per WAVE. FMA balance: 114 / 112 / 105 / 108
constexpr unsigned GMASK[4] = {0xE0010u, 0x700100u, 0x7C00u, 0x182EFu};

__device__ __forceinline__ int imx(int a, int b){ return a > b ? a : b; }
__device__ __forceinline__ int imn(int a, int b){ return a < b ? a : b; }

__device__ __forceinline__ double factd(int n){
    double r = 1.0;
    for(int i = 2; i <= n; ++i) r *= (double)i;
    return r;
}

// ---------------------------------------------------------------------------
// Setup kernel: replicate the reference's _wigner_3j EXACTLY (verified R0).
// ---------------------------------------------------------------------------
__global__ __launch_bounds__(512) void cg_setup(float* __restrict__ cg_out){
    const int p  = blockIdx.x;
    const int j1 = L1[p], j2 = L2[p], j3 = L3[p];
    const int n1 = 2*j1+1, n2 = 2*j2+1, n3 = 2*j3+1;
    const int ntot = n1*n2*n3;
    const int t = threadIdx.x;

    __shared__ double scg[343];
    __shared__ double qre[3][49];
    __shared__ double qim[3][49];
    __shared__ double red[512];

    if(t < ntot){
        int a   = t / (n2*n3);
        int rem = t - a*(n2*n3);
        int b   = rem / n3;
        int g   = rem - b*n3;
        int m1 = a - j1, m2 = b - j2, m3 = g - j3;
        double val = 0.0;
        if(m1 + m2 == m3){
            int vmin = imx(imx(-j1 + j2 + m3, -j1 + m1), 0);
            int vmax = imn(imn(j2 + j3 + m1, j3 - j1 + j2), j3 + m3);
            double C = sqrt((2.0*j3 + 1.0) * factd(j3 + j1 - j2) * factd(j3 - j1 + j2)
                            * factd(j1 + j2 - j3) / factd(j1 + j2 + j3 + 1));
            C *= sqrt(factd(j3 + m3) * factd(j3 - m3) * factd(j1 - m1)
                      * factd(j1 + m1) * factd(j2 - m2) * factd(j2 + m2));
            double S = 0.0;
            for(int v = vmin; v <= vmax; ++v){
                double sgn = ((v + j2 + m2) & 1) ? -1.0 : 1.0;
                S += sgn * factd(j2 + j3 + m1 - v) * factd(j1 - m1 + v)
                     / (factd(v) * factd(j3 - j1 + j2 - v) * factd(j3 + m3 - v)
                        * factd(v + j1 - j2 - m3));
            }
            val = C * S;
        }
        scg[t] = val;
    }

    if(t < 3){
        int l = (t == 0) ? j1 : ((t == 1) ? j2 : j3);
        int n = 2*l + 1;
        double* QR = qre[t];
        double* QI = qim[t];
        for(int i = 0; i < 49; ++i){ QR[i] = 0.0; QI[i] = 0.0; }
        const double is2 = 0.70710678118654752440;
        for(int m = -l; m < 0; ++m){
            QR[(l+m)*n + (l-m)] = is2;
            QI[(l+m)*n + (l+m)] = -is2;
        }
        QR[l*n + l] = 1.0;
        for(int m = 1; m <= l; ++m){
            double s = (m & 1) ? -1.0 : 1.0;
            QR[(l+m)*n + (l+m)] = s * is2;
            QI[(l+m)*n + (l-m)] = s * is2;
        }
        double fr, fi;
        switch(l & 3){
            case 0: fr = 1.0;  fi = 0.0;  break;
            case 1: fr = 0.0;  fi = -1.0; break;
            case 2: fr = -1.0; fi = 0.0;  break;
            default: fr = 0.0; fi = 1.0;  break;
        }
        for(int i = 0; i < n*n; ++i){
            double re = QR[i], im = QI[i];
            QR[i] = re*fr - im*fi;
            QI[i] = re*fi + im*fr;
        }
    }
    __syncthreads();

    double val = 0.0;
    if(t < ntot){
        int j   = t / (n2*n3);
        int rem = t - j*(n2*n3);
        int lq  = rem / n3;
        int m   = rem - lq*n3;
        double acc = 0.0;
        for(int i = 0; i < n1; ++i){
            double q1r = qre[0][i*n1 + j], q1i = qim[0][i*n1 + j];
            if(q1r == 0.0 && q1i == 0.0) continue;
            for(int k = 0; k < n2; ++k){
                double q2r = qre[1][k*n2 + lq], q2i = qim[1][k*n2 + lq];
                if(q2r == 0.0 && q2i == 0.0) continue;
                double ar = q1r*q2r - q1i*q2i;
                double ai = q1r*q2i + q1i*q2r;
                for(int n = 0; n < n3; ++n){
                    double cv = scg[(i*n2 + k)*n3 + n];
                    if(cv == 0.0) continue;
                    double q3r = qre[2][n*n3 + m];
                    double q3i = -qim[2][n*n3 + m];
                    acc += cv * (ar*q3r - ai*q3i);
                }
            }
        }
        val = acc;
    }

    red[t] = val * val;
    __syncthreads();
    for(int s = 256; s > 0; s >>= 1){
        if(t < s) red[t] += red[t + s];
        __syncthreads();
    }
    double nrm = sqrt(red[0]);
    if(t < ntot){
        cg_out[CGOFF[p] + t] = (float)(val * sqrt(2.0*j3 + 1.0) / nrm);
    }
}

// ---------------------------------------------------------------------------
// Phase C, templated on path group -> compile-time mask -> straight-line code
// (no branches, w already in registers, LDS reads + FMAs freely schedulable).
// ---------------------------------------------------------------------------
template<int G>
__device__ __forceinline__ void phaseC(const float* __restrict__ xr,
                                       const float* __restrict__ wreg,
                                       const float* __restrict__ Te,
                                       float* __restrict__ ob)
{
    constexpr unsigned mask = GMASK[G];
    #pragma unroll
    for(int p = 0; p < NPATH; ++p){
        if(!((mask >> p) & 1u)) continue;   // folds at compile time after unroll
        const int n1 = 2*L1[p] + 1;
        const int n3 = 2*L3[p] + 1;
        const int o1 = LOFF[L1[p]];
        const float wp = wreg[p];
        const float* Tp = Te + TOFF[p];
        #pragma unroll
        for(int k = 0; k < n3; ++k){
            float acc = 0.f;
            #pragma unroll
            for(int i = 0; i < n1; ++i)
                acc = fmaf(xr[o1 + i], Tp[i*n3 + k], acc);
            ob[OOFF[p] + k] = wp * acc;
        }
    }
}

// ---------------------------------------------------------------------------
// Main kernel: 2 edges/block, 256 threads, wave = path group, lane = (el, c).
// x and ALL 23 w values prefetched into registers before the phase-B barrier
// (latency hidden under phase B). Outputs staged in LDS, coalesced flush.
// ---------------------------------------------------------------------------
__global__ __launch_bounds__(256, 5) void tp_main(
    const float* __restrict__ x, const float* __restrict__ y,
    const float* __restrict__ w, const float* __restrict__ cg,
    float* __restrict__ out)
{
    __shared__ __align__(16) float obuf[EPB*NCHAN*OUTW];  // 6336 floats, 25.3 KB
    __shared__ float Ts[EPB*TTOT];                        // 878 floats, 3.5 KB
    __shared__ float ys[EPB*16];                          // 32 floats

    const int tid = threadIdx.x;
    const int e0  = blockIdx.x * EPB;

    const int c   = tid & 31;          // channel
    const int el  = (tid >> 5) & 1;    // edge within block
    const int grp = tid >> 6;          // wave id = path group
    const int e   = e0 + el;

    // --- prefetch x (4x float4) and all 23 w scalars into registers ---
    const float4* xp = reinterpret_cast<const float4*>(x + (size_t)(e*NCHAN + c)*16);
    float4 x0 = xp[0], x1 = xp[1], x2 = xp[2], x3 = xp[3];

    const float* wrow = w + (size_t)e*NWROW + c;
    float wreg[NPATH];
    #pragma unroll
    for(int p = 0; p < NPATH; ++p)
        wreg[p] = wrow[POS[p]*NCHAN];   // static offsets; issued before barrier

    if(tid < EPB*16) ys[tid] = y[e0*16 + tid];
    __syncthreads();

    // Phase B: T[el][p][i][k] = sum_j y[el][o2+j] * CG[p][i][j][k]  (878 items)
    for(int u = tid; u < EPB*TTOT; u += 256){
        int eli = u / TTOT;
        int v   = u - eli*TTOT;
        int p   = 0;
        while(p < NPATH-1 && TOFF[p+1] <= v) ++p;
        int rel = v - TOFF[p];
        int n2  = 2*L2[p] + 1;
        int n3  = 2*L3[p] + 1;
        int i   = rel / n3;
        int k   = rel - i*n3;
        int o2  = LOFF[L2[p]];
        const float* cgp = &cg[CGOFF[p]];
        float acc = 0.f;
        for(int j = 0; j < n2; ++j)
            acc += ys[eli*16 + o2 + j] * cgp[(i*n2 + j)*n3 + k];
        Ts[u] = acc;
    }
    __syncthreads();

    // Phase C: straight-line per-wave path group
    float xr[16];
    xr[0]=x0.x;  xr[1]=x0.y;  xr[2]=x0.z;  xr[3]=x0.w;
    xr[4]=x1.x;  xr[5]=x1.y;  xr[6]=x1.z;  xr[7]=x1.w;
    xr[8]=x2.x;  xr[9]=x2.y;  xr[10]=x2.z; xr[11]=x2.w;
    xr[12]=x3.x; xr[13]=x3.y; xr[14]=x3.z; xr[15]=x3.w;

    const float* Te = Ts + el*TTOT;
    float* ob = obuf + el*(NCHAN*OUTW) + c*OUTW;

    switch(grp){
        case 0: phaseC<0>(xr, wreg, Te, ob); break;
        case 1: phaseC<1>(xr, wreg, Te, ob); break;
        case 2: phaseC<2>(xr, wreg, Te, ob); break;
        default: phaseC<3>(xr, wreg, Te, ob); break;
    }
    __syncthreads();

    // Flush: 6336 contiguous floats -> coalesced float4 stores (64B-aligned)
    const float4* ob4 = reinterpret_cast<const float4*>(obuf);
    float4* o4 = reinterpret_cast<float4*>(out + (size_t)blockIdx.x * (EPB*NCHAN*OUTW));
    #pragma unroll
    for(int idx = tid; idx < EPB*NCHAN*OUTW/4; idx += 256)
        o4[idx] = ob4[idx];
}

extern "C" void kernel_launch(void* const* d_in, const int* in_sizes, int n_in,
                              void* d_out, int out_size, void* d_ws, size_t ws_size,
                              hipStream_t stream)
{
    const float* x  = (const float*)d_in[0];
    const float* y  = (const float*)d_in[1];
    const float* wt = (const float*)d_in[2];
    float* out = (float*)d_out;
    float* cgw = (float*)d_ws;   // 1875 floats = 7.5 KB of scratch

    cg_setup<<<NPATH, 512, 0, stream>>>(cgw);
    tp_main<<<NEDGE/EPB, 256, 0, stream>>>(x, y, wt, cgw, out);
}